// Round 5
// baseline (700.738 us; speedup 1.0000x reference)
//
#include <hip/hip_runtime.h>
#include <math.h>

#define VOCAB 100000
#define BATCH 4096
#define DOC_LEN 200
#define EMBED_DIM 300
#define NUM_CLASSES 20

// ---------------------------------------------------------------------------
// Kernel 1:  P[v][c] = sum_k emb[v][k] * (W[c][k]/DOC_LEN)
// K-split: 5 waves = 5 disjoint 60-dim slices (each emb element read ONCE,
// round-4 lesson: class-split's 5x load-issue was the stall) x R=2 rows/lane.
// NO forced min-occupancy (round-2 lesson: bounds(320,4) -> 64 VGPR -> spill).
// Explicit 2-deep load pipeline caps live float4s at 12 (~100 VGPR total).
// W in LDS (round-3 lesson: scalar K$ thrash), pre-scaled by 1/DOC_LEN.
// Slice partials in LDS [5][128][20] = 51.2 KB unioned with W -> 3 blocks/CU
// = 15 waves/CU, matching the 782-block grid (3.05 blocks/CU).
// ---------------------------------------------------------------------------
#define K1_BLOCK 320
#define K1_RPB   128                                  // rows per block
#define K1_GRID  ((VOCAB + K1_RPB - 1) / K1_RPB)      // 782

__global__ __launch_bounds__(K1_BLOCK) void project_kernel(
    const float* __restrict__ emb,   // (VOCAB, 300)
    const float* __restrict__ W,     // (20, 300)
    float*       __restrict__ P)     // (VOCAB, 20)  [workspace]
{
    // union: sW (6000 floats) during compute; partials [5][128][20] after
    __shared__ float smem[5 * K1_RPB * NUM_CLASSES];  // 51200 B

    float* sW = smem;
    const float inv = 1.0f / (float)DOC_LEN;
    for (int i = threadIdx.x; i < NUM_CLASSES * EMBED_DIM; i += K1_BLOCK)
        sW[i] = W[i] * inv;                           // fold mean into W
    __syncthreads();

    const int s    = threadIdx.x >> 6;                // k-slice = wave id, 0..4
    const int lane = threadIdx.x & 63;
    const int rbase = blockIdx.x * K1_RPB;
    const int r0 = rbase + lane;
    const int r1 = r0 + 64;
    const float* __restrict__ e0 =
        emb + (size_t)(r0 < VOCAB ? r0 : VOCAB - 1) * EMBED_DIM + s * 60;
    const float* __restrict__ e1 =
        emb + (size_t)(r1 < VOCAB ? r1 : VOCAB - 1) * EMBED_DIM + s * 60;
    const float* wS = sW + s * 60;                    // W[c][60s + ...]

    float acc0[NUM_CLASSES], acc1[NUM_CLASSES];
    #pragma unroll
    for (int c = 0; c < NUM_CLASSES; ++c) { acc0[c] = 0.0f; acc1[c] = 0.0f; }

    // 60-dim slice = 5 chunks of 12; 2-deep pipeline: load k+12 while fma k
    float4 a0 = *reinterpret_cast<const float4*>(e0);
    float4 a1 = *reinterpret_cast<const float4*>(e0 + 4);
    float4 a2 = *reinterpret_cast<const float4*>(e0 + 8);
    float4 b0 = *reinterpret_cast<const float4*>(e1);
    float4 b1 = *reinterpret_cast<const float4*>(e1 + 4);
    float4 b2 = *reinterpret_cast<const float4*>(e1 + 8);

    #pragma unroll
    for (int kk = 0; kk < 5; ++kk) {
        float4 na0, na1, na2, nb0, nb1, nb2;
        if (kk < 4) {
            const int nk = 12 * (kk + 1);
            na0 = *reinterpret_cast<const float4*>(e0 + nk);
            na1 = *reinterpret_cast<const float4*>(e0 + nk + 4);
            na2 = *reinterpret_cast<const float4*>(e0 + nk + 8);
            nb0 = *reinterpret_cast<const float4*>(e1 + nk);
            nb1 = *reinterpret_cast<const float4*>(e1 + nk + 4);
            nb2 = *reinterpret_cast<const float4*>(e1 + nk + 8);
        }
        const int k = 12 * kk;
        #pragma unroll
        for (int cc = 0; cc < NUM_CLASSES; ++cc) {
            const float* wc = wS + cc * EMBED_DIM + k;   // wave-uniform -> broadcast
            const float4 w0 = *reinterpret_cast<const float4*>(wc);
            const float4 w1 = *reinterpret_cast<const float4*>(wc + 4);
            const float4 w2 = *reinterpret_cast<const float4*>(wc + 8);
            acc0[cc] += a0.x*w0.x + a0.y*w0.y + a0.z*w0.z + a0.w*w0.w
                      + a1.x*w1.x + a1.y*w1.y + a1.z*w1.z + a1.w*w1.w
                      + a2.x*w2.x + a2.y*w2.y + a2.z*w2.z + a2.w*w2.w;
            acc1[cc] += b0.x*w0.x + b0.y*w0.y + b0.z*w0.z + b0.w*w0.w
                      + b1.x*w1.x + b1.y*w1.y + b1.z*w1.z + b1.w*w1.w
                      + b2.x*w2.x + b2.y*w2.y + b2.z*w2.z + b2.w*w2.w;
        }
        if (kk < 4) {
            a0 = na0; a1 = na1; a2 = na2;
            b0 = nb0; b1 = nb1; b2 = nb2;
        }
    }
    __syncthreads();   // everyone done reading sW

    // partials: [s][r][20], contiguous (2-way/8-way write aliasing, one-time)
    float* sPart = smem;
    #pragma unroll
    for (int cc = 0; cc < NUM_CLASSES; ++cc) {
        sPart[(s * K1_RPB + lane) * NUM_CLASSES + cc]        = acc0[cc];
        sPart[(s * K1_RPB + lane + 64) * NUM_CLASSES + cc]   = acc1[cc];
    }
    __syncthreads();

    // reduce 5 slices; 2560 outputs, 8 per thread; fully linear stores
    #pragma unroll
    for (int j = 0; j < 8; ++j) {
        const int oi = threadIdx.x + j * K1_BLOCK;     // 0..2559 = r*20 + c
        float v = sPart[oi]
                + sPart[1 * K1_RPB * NUM_CLASSES + oi]
                + sPart[2 * K1_RPB * NUM_CLASSES + oi]
                + sPart[3 * K1_RPB * NUM_CLASSES + oi]
                + sPart[4 * K1_RPB * NUM_CLASSES + oi];
        const int gr = rbase + oi / NUM_CLASSES;
        if (gr < VOCAB)
            P[(size_t)rbase * NUM_CLASSES + oi] = v;
    }
}

// ---------------------------------------------------------------------------
// Kernel 2: out[doc] = softmax( sum_l P[x[doc][l]] + b )   (unchanged)
// One wave per doc; 64 lanes = 3 position-groups x 20 classes.
// ---------------------------------------------------------------------------
#define K2_BLOCK 256
#define DOCS_PER_BLOCK 4

__global__ __launch_bounds__(K2_BLOCK) void pool_softmax_kernel(
    const float* __restrict__ P,     // (VOCAB, 20), pre-scaled by 1/DOC_LEN
    const float* __restrict__ bias,  // (20,)
    const int*   __restrict__ x,     // (BATCH, 200)
    float*       __restrict__ out)   // (BATCH, 20)
{
    __shared__ int sidx[DOCS_PER_BLOCK][DOC_LEN];

    const int doc0 = blockIdx.x * DOCS_PER_BLOCK;
    const int tid  = threadIdx.x;

    for (int i = tid; i < DOCS_PER_BLOCK * DOC_LEN; i += K2_BLOCK)
        (&sidx[0][0])[i] = x[doc0 * DOC_LEN + i];
    __syncthreads();

    const int wave = tid >> 6;
    const int lane = tid & 63;
    const int doc  = doc0 + wave;
    const int g    = lane / NUM_CLASSES;          // 0..2 active, 3 idle
    const int c    = lane - g * NUM_CLASSES;

    float acc = 0.0f;
    if (g < 3) {
        #pragma unroll 4
        for (int l = g; l < DOC_LEN; l += 3) {
            const int row = sidx[wave][l];        // LDS broadcast per group
            acc += P[(size_t)row * NUM_CLASSES + c];
        }
    }

    const float a1 = __shfl(acc, lane + 20, 64);
    const float a2 = __shfl(acc, lane + 40, 64);

    float v = (lane < NUM_CLASSES) ? (acc + a1 + a2 + bias[c]) : -INFINITY;

    float m = v;
    #pragma unroll
    for (int off = 16; off > 0; off >>= 1)
        m = fmaxf(m, __shfl_xor(m, off, 32));
    const float e = (lane < NUM_CLASSES) ? expf(v - m) : 0.0f;
    float s = e;
    #pragma unroll
    for (int off = 16; off > 0; off >>= 1)
        s += __shfl_xor(s, off, 32);

    if (lane < NUM_CLASSES)
        out[doc * NUM_CLASSES + lane] = e / s;
}

extern "C" void kernel_launch(void* const* d_in, const int* in_sizes, int n_in,
                              void* d_out, int out_size, void* d_ws, size_t ws_size,
                              hipStream_t stream) {
    const float* emb  = (const float*)d_in[0];
    const float* W    = (const float*)d_in[1];
    const float* bias = (const float*)d_in[2];
    const int*   x    = (const int*)d_in[3];
    float* out = (float*)d_out;
    float* P   = (float*)d_ws;   // needs VOCAB*20*4 = 8,000,000 B

    project_kernel<<<K1_GRID, K1_BLOCK, 0, stream>>>(emb, W, P);
    pool_softmax_kernel<<<BATCH / DOCS_PER_BLOCK, K2_BLOCK, 0, stream>>>(P, bias, x, out);
}